// Round 17
// baseline (397.015 us; speedup 1.0000x reference)
//
#include <hip/hip_runtime.h>
#include <hip/hip_bf16.h>

// Problem constants (fixed by the reference)
#define NN 50000
#define EE 800000
#define E2 850000      // EE + NN self loops
#define HC 128         // HEADS*HIDDEN
#define HEADS 8
#define HID 16
#define NC 10
#define NEG_SLOPE 0.2f

#define SCAN_B 256
#define NBLK ((NN + SCAN_B - 1) / SCAN_B)   // 196

// Atomic-free CSR build: P edge-chunks, 2 histogram passes of HALF bins
#define P 64
#define CHUNK ((E2 + P - 1) / P)            // 13282
#define HALF 25000                          // 100 KB LDS histogram

// bf16 pack/unpack (H table stored as packed bf16x2 to halve gather bytes)
__device__ inline unsigned pack_bf16x2(float x, float y) {
    unsigned ux = __float_as_uint(x); ux = (ux + 0x7FFFu + ((ux >> 16) & 1u)) >> 16;
    unsigned uy = __float_as_uint(y); uy = (uy + 0x7FFFu + ((uy >> 16) & 1u)) >> 16;
    return ux | (uy << 16);
}
__device__ inline float bf_lo(unsigned u) { return __uint_as_float(u << 16); }
__device__ inline float bf_hi(unsigned u) { return __uint_as_float(u & 0xFFFF0000u); }

// ---------------------------------------------------------------------------
// CSR build v2 — no global atomics (round-13 profile: 850k device-scope
// atomics cost 64B coherent traffic each; scatter WRITE_SIZE was 54.5 MB
// = 850k x 64B. LDS histograms + plain stores instead).
// ---------------------------------------------------------------------------
__global__ __launch_bounds__(256) void hist_kernel(
    const int* __restrict__ ei, int* __restrict__ Hh)
{
    __shared__ int hist[HALF];
    const int b = blockIdx.x, t = threadIdx.x;
    const int e0 = b * CHUNK;
    const int e1 = min(e0 + CHUNK, E2);
    for (int pass = 0; pass < 2; ++pass) {
        const int base = pass * HALF;
        for (int i = t; i < HALF; i += 256) hist[i] = 0;
        __syncthreads();
        for (int e = e0 + t; e < e1; e += 256) {
            int dst = (e < EE) ? ei[EE + e] : (e - EE);
            int d = dst - base;
            if (d >= 0 && d < HALF) atomicAdd(&hist[d], 1);   // LDS atomic
        }
        __syncthreads();
        int* outp = Hh + (size_t)b * NN + base;
        for (int i = t; i < HALF; i += 256) outp[i] = hist[i];
        __syncthreads();
    }
}

__global__ __launch_bounds__(256) void colsum_kernel(
    const int* __restrict__ Hh, int* __restrict__ deg)
{
    int n = blockIdx.x * 256 + threadIdx.x;
    if (n >= NN) return;
    int s = 0;
    #pragma unroll 8
    for (int b = 0; b < P; ++b) s += Hh[(size_t)b * NN + n];   // coalesced per b
    deg[n] = s;
}

__global__ __launch_bounds__(SCAN_B) void scan1_kernel(
    const int* __restrict__ deg, int* __restrict__ rowptr, int* __restrict__ bsum)
{
    __shared__ int sm[SCAN_B];
    const int b = blockIdx.x, t = threadIdx.x, i = b * SCAN_B + t;
    int v = (i < NN) ? deg[i] : 0;
    sm[t] = v;
    __syncthreads();
    for (int off = 1; off < SCAN_B; off <<= 1) {
        int x = (t >= off) ? sm[t - off] : 0;
        __syncthreads();
        sm[t] += x;
        __syncthreads();
    }
    if (i < NN) rowptr[i] = sm[t] - v;          // local exclusive
    if (t == SCAN_B - 1) bsum[b] = sm[t];       // block total
}

__global__ __launch_bounds__(SCAN_B) void scan2_kernel(
    int* __restrict__ bsum, int* __restrict__ rowptr)
{
    __shared__ int sm[SCAN_B];
    const int t = threadIdx.x;
    int v = (t < NBLK) ? bsum[t] : 0;
    sm[t] = v;
    __syncthreads();
    for (int off = 1; off < SCAN_B; off <<= 1) {
        int x = (t >= off) ? sm[t - off] : 0;
        __syncthreads();
        sm[t] += x;
        __syncthreads();
    }
    if (t < NBLK) bsum[t] = sm[t] - v;          // exclusive block offsets
    if (t == NBLK - 1) rowptr[NN] = sm[t];      // grand total (= E2)
}

__global__ __launch_bounds__(SCAN_B) void scan3_kernel(
    int* __restrict__ rowptr, const int* __restrict__ bsum)
{
    const int b = blockIdx.x, i = b * SCAN_B + threadIdx.x;
    if (i < NN) rowptr[i] += bsum[b];
}

// In-place: Hh[b][n] (count) -> global write offset for chunk b, node n
__global__ __launch_bounds__(256) void offset_kernel(
    int* __restrict__ Hh, const int* __restrict__ rowptr)
{
    int n = blockIdx.x * 256 + threadIdx.x;
    if (n >= NN) return;
    int run = rowptr[n];
    #pragma unroll 8
    for (int b = 0; b < P; ++b) {
        size_t idx = (size_t)b * NN + n;
        int c = Hh[idx];
        Hh[idx] = run;
        run += c;
    }
}

__global__ __launch_bounds__(256) void scatter2_kernel(
    const int* __restrict__ ei, const int* __restrict__ Hh,
    int* __restrict__ srcs)
{
    __shared__ int hist[HALF];
    const int b = blockIdx.x, t = threadIdx.x;
    const int e0 = b * CHUNK;
    const int e1 = min(e0 + CHUNK, E2);
    const int* offp = Hh + (size_t)b * NN;
    for (int pass = 0; pass < 2; ++pass) {
        const int base = pass * HALF;
        for (int i = t; i < HALF; i += 256) hist[i] = 0;
        __syncthreads();
        for (int e = e0 + t; e < e1; e += 256) {
            int src, dst;
            if (e < EE) { src = ei[e]; dst = ei[EE + e]; }
            else        { src = e - EE; dst = e - EE; }
            int d = dst - base;
            if (d >= 0 && d < HALF) {
                int rank = atomicAdd(&hist[d], 1);          // LDS atomic
                srcs[offp[dst] + rank] = src;               // plain store, L2-absorbed
            }
        }
        __syncthreads();
    }
}

// ---------------------------------------------------------------------------
// Fused GEMM (X[N,128] @ W[128,128]) + per-head alpha_src/alpha_dst dots.
// 512 threads, 131 KB LDS -> 1 block/CU, 2 waves/SIMD.
// H is written PACKED bf16 (row = 64 uints = 256 B) for the gather phase.
// ---------------------------------------------------------------------------
__global__ __launch_bounds__(512) void gemm_fused_kernel(
    const float* __restrict__ X, const float* __restrict__ W,
    const float* __restrict__ asrc, const float* __restrict__ adst,
    unsigned* __restrict__ Hb, float* __restrict__ AS, float* __restrict__ AD)
{
    __shared__ float Ws[8 * 2052];     // plane h: h*2052 + k*16 + j (bank-disjoint heads)
    __shared__ float Xst[128 * 128];   // Xst[k*128 + r]
    const int tid = threadIdx.x;
    const int row0 = blockIdx.x * 128;

    for (int i = tid; i < 4096; i += 512) {
        int k = i >> 5, q = i & 31;
        float4 v = ((const float4*)W)[i];
        *(float4*)&Ws[(q >> 2) * 2052 + k * 16 + (q & 3) * 4] = v;
    }
    {
        int r = tid & 127, quarter = tid >> 7;   // 0..3
        int row = row0 + r;
        if (row < NN) {
            const float4* xr = (const float4*)(X + (size_t)row * HC + quarter * 32);
            #pragma unroll
            for (int c4 = 0; c4 < 8; ++c4) {
                float4 v = xr[c4];
                int c = quarter * 32 + c4 * 4;
                Xst[(c + 0) * 128 + r] = v.x;
                Xst[(c + 1) * 128 + r] = v.y;
                Xst[(c + 2) * 128 + r] = v.z;
                Xst[(c + 3) * 128 + r] = v.w;
            }
        } else {
            #pragma unroll
            for (int c4 = 0; c4 < 8; ++c4) {
                int c = quarter * 32 + c4 * 4;
                Xst[(c + 0) * 128 + r] = 0.f;
                Xst[(c + 1) * 128 + r] = 0.f;
                Xst[(c + 2) * 128 + r] = 0.f;
                Xst[(c + 3) * 128 + r] = 0.f;
            }
        }
    }
    __syncthreads();

    const int rg = tid >> 3;     // 0..63 -> rows rg*2, rg*2+1
    const int head = tid & 7;
    float acc[2][16];
    #pragma unroll
    for (int i = 0; i < 2; ++i)
        #pragma unroll
        for (int j = 0; j < 16; ++j) acc[i][j] = 0.f;

    const float* wbase = &Ws[head * 2052];
    #pragma unroll 4
    for (int k = 0; k < 128; ++k) {
        float2 xv = *(const float2*)&Xst[k * 128 + rg * 2];
        const float* wp = wbase + k * 16;
        float4 w0 = *(const float4*)(wp + 0);
        float4 w1 = *(const float4*)(wp + 4);
        float4 w2 = *(const float4*)(wp + 8);
        float4 w3 = *(const float4*)(wp + 12);
        float xs[2] = {xv.x, xv.y};
        float ww[16] = {w0.x, w0.y, w0.z, w0.w, w1.x, w1.y, w1.z, w1.w,
                        w2.x, w2.y, w2.z, w2.w, w3.x, w3.y, w3.z, w3.w};
        #pragma unroll
        for (int i = 0; i < 2; ++i)
            #pragma unroll
            for (int j = 0; j < 16; ++j)
                acc[i][j] = fmaf(xs[i], ww[j], acc[i][j]);
    }

    // Epilogue: packed-bf16 H rows + fp32 per-head alpha dots
    #pragma unroll
    for (int i = 0; i < 2; ++i) {
        int row = row0 + rg * 2 + i;
        if (row >= NN) continue;
        unsigned* hp = Hb + (size_t)row * 64 + head * 8;
        uint4 p0 = make_uint4(pack_bf16x2(acc[i][0],  acc[i][1]),
                              pack_bf16x2(acc[i][2],  acc[i][3]),
                              pack_bf16x2(acc[i][4],  acc[i][5]),
                              pack_bf16x2(acc[i][6],  acc[i][7]));
        uint4 p1 = make_uint4(pack_bf16x2(acc[i][8],  acc[i][9]),
                              pack_bf16x2(acc[i][10], acc[i][11]),
                              pack_bf16x2(acc[i][12], acc[i][13]),
                              pack_bf16x2(acc[i][14], acc[i][15]));
        ((uint4*)hp)[0] = p0;
        ((uint4*)hp)[1] = p1;
        float s = 0.f, d = 0.f;
        #pragma unroll
        for (int j = 0; j < 16; ++j) {
            s = fmaf(acc[i][j], asrc[head * HID + j], s);
            d = fmaf(acc[i][j], adst[head * HID + j], d);
        }
        AS[row * HEADS + head] = s;
        AD[row * HEADS + head] = d;
    }
}

// ---------------------------------------------------------------------------
// Aggregation v3: 256-thread block = 4 independent waves, wave = one node.
// Lane covers 2 channels (one packed-bf16 uint = 4B coalesced load/edge).
// 4-way edge unroll -> 4 independent gather chains in flight per wave.
// ---------------------------------------------------------------------------
__global__ __launch_bounds__(256) void aggregate_kernel(
    const unsigned* __restrict__ Hb, const float* __restrict__ AS,
    const float* __restrict__ AD, const int* __restrict__ srcs,
    const int* __restrict__ rowptr, const float* __restrict__ bias,
    float* __restrict__ Out)
{
    const int wave = threadIdx.x >> 6;
    const int lane = threadIdx.x & 63;
    const int n = blockIdx.x * 4 + wave;
    if (n >= NN) return;
    const int head = lane >> 3;                 // head of channels 2*lane, 2*lane+1
    const int beg = rowptr[n], end = rowptr[n + 1];
    const float adv = AD[n * HEADS + head];

    float a0x = 0.f, a0y = 0.f, a1x = 0.f, a1y = 0.f;
    float a2x = 0.f, a2y = 0.f, a3x = 0.f, a3y = 0.f;
    float d0 = 0.f, d1 = 0.f, d2 = 0.f, d3 = 0.f;

    int s = beg;
    for (; s + 3 < end; s += 4) {
        int s0 = srcs[s], s1 = srcs[s + 1], s2 = srcs[s + 2], s3 = srcs[s + 3];
        float e0 = AS[s0 * HEADS + head] + adv;
        float e1 = AS[s1 * HEADS + head] + adv;
        float e2 = AS[s2 * HEADS + head] + adv;
        float e3 = AS[s3 * HEADS + head] + adv;
        unsigned h0 = Hb[(size_t)s0 * 64 + lane];
        unsigned h1 = Hb[(size_t)s1 * 64 + lane];
        unsigned h2 = Hb[(size_t)s2 * 64 + lane];
        unsigned h3 = Hb[(size_t)s3 * 64 + lane];
        e0 = (e0 >= 0.f) ? e0 : NEG_SLOPE * e0;
        e1 = (e1 >= 0.f) ? e1 : NEG_SLOPE * e1;
        e2 = (e2 >= 0.f) ? e2 : NEG_SLOPE * e2;
        e3 = (e3 >= 0.f) ? e3 : NEG_SLOPE * e3;
        float w0 = __expf(e0), w1 = __expf(e1), w2 = __expf(e2), w3 = __expf(e3);
        d0 += w0; d1 += w1; d2 += w2; d3 += w3;
        a0x = fmaf(w0, bf_lo(h0), a0x); a0y = fmaf(w0, bf_hi(h0), a0y);
        a1x = fmaf(w1, bf_lo(h1), a1x); a1y = fmaf(w1, bf_hi(h1), a1y);
        a2x = fmaf(w2, bf_lo(h2), a2x); a2y = fmaf(w2, bf_hi(h2), a2y);
        a3x = fmaf(w3, bf_lo(h3), a3x); a3y = fmaf(w3, bf_hi(h3), a3y);
    }
    for (; s < end; ++s) {
        int s0 = srcs[s];
        float e0 = AS[s0 * HEADS + head] + adv;
        unsigned h0 = Hb[(size_t)s0 * 64 + lane];
        e0 = (e0 >= 0.f) ? e0 : NEG_SLOPE * e0;
        float w0 = __expf(e0);
        d0 += w0;
        a0x = fmaf(w0, bf_lo(h0), a0x); a0y = fmaf(w0, bf_hi(h0), a0y);
    }
    float den = (d0 + d1) + (d2 + d3);
    float ax = (a0x + a1x) + (a2x + a3x);
    float ay = (a0y + a1y) + (a2y + a3y);
    float2 bv = *(const float2*)&bias[2 * lane];
    float ox = fmaxf(ax / den + bv.x, 0.f);
    float oy = fmaxf(ay / den + bv.y, 0.f);
    *(float2*)&Out[(size_t)n * HC + 2 * lane] = make_float2(ox, oy);
}

// ---------------------------------------------------------------------------
// Output GEMM: X[N,128] @ Wout[128,10] + bout
// ---------------------------------------------------------------------------
__global__ __launch_bounds__(256) void out_gemm_kernel(
    const float* __restrict__ X, const float* __restrict__ W,
    const float* __restrict__ b, float* __restrict__ Out)
{
    __shared__ float Ws[HC * NC];
    __shared__ float bs[NC];
    for (int i = threadIdx.x; i < HC * NC; i += 256) Ws[i] = W[i];
    if (threadIdx.x < NC) bs[threadIdx.x] = b[threadIdx.x];
    __syncthreads();
    int row = blockIdx.x * 256 + threadIdx.x;
    if (row >= NN) return;
    float acc[NC];
    #pragma unroll
    for (int j = 0; j < NC; ++j) acc[j] = bs[j];
    const float4* xr = (const float4*)(X + (size_t)row * HC);
    #pragma unroll 8
    for (int k4 = 0; k4 < 32; ++k4) {
        float4 v = xr[k4];
        const float* w0 = &Ws[(k4 * 4 + 0) * NC];
        const float* w1 = &Ws[(k4 * 4 + 1) * NC];
        const float* w2 = &Ws[(k4 * 4 + 2) * NC];
        const float* w3 = &Ws[(k4 * 4 + 3) * NC];
        #pragma unroll
        for (int j = 0; j < NC; ++j)
            acc[j] += v.x * w0[j] + v.y * w1[j] + v.z * w2[j] + v.w * w3[j];
    }
    float* op = Out + (size_t)row * NC;
    #pragma unroll
    for (int j = 0; j < NC; ++j) op[j] = acc[j];
}

// ---------------------------------------------------------------------------
extern "C" void kernel_launch(void* const* d_in, const int* in_sizes, int n_in,
                              void* d_out, int out_size, void* d_ws, size_t ws_size,
                              hipStream_t stream)
{
    const float* x      = (const float*)d_in[0];
    const int*   ei     = (const int*)d_in[1];   // edge_index as int32 [2,E]
    const float* W1     = (const float*)d_in[2];
    const float* asrc1  = (const float*)d_in[3];
    const float* adst1  = (const float*)d_in[4];
    const float* b1     = (const float*)d_in[5];
    const float* W2     = (const float*)d_in[6];
    const float* asrc2  = (const float*)d_in[7];
    const float* adst2  = (const float*)d_in[8];
    const float* b2     = (const float*)d_in[9];
    const float* Wout   = (const float*)d_in[10];
    const float* bout   = (const float*)d_in[11];
    float* out = (float*)d_out;

    // Workspace layout — exact requirement check first (~58.2 MB).
    const size_t need_bytes =
        (size_t)NN * 64 * sizeof(unsigned) +                       // hb
        ((size_t)NN * HC + (size_t)NN * HEADS * 2) * sizeof(float) + // x2, as, ad
        ((size_t)(NN + 1) + NN + E2 + NBLK + (size_t)P * NN) * sizeof(int);
    if (ws_size < need_bytes) return;   // clean fail beats a memory fault

    unsigned* hb = (unsigned*)d_ws;                  // N*64 (packed bf16)
    float* x2  = (float*)(hb + (size_t)NN * 64);     // N*128
    float* as_ = x2 + (size_t)NN * HC;               // N*8
    float* ad_ = as_ + (size_t)NN * HEADS;           // N*8
    int* rowptr = (int*)(ad_ + (size_t)NN * HEADS);  // N+1
    int* deg    = rowptr + (NN + 1);                 // N
    int* srcs   = deg + NN;                          // E2
    int* bsum   = srcs + E2;                         // NBLK
    int* Hh     = bsum + NBLK;                       // P*N (counts -> offsets)

    // CSR build — no global atomics
    hist_kernel<<<P, 256, 0, stream>>>(ei, Hh);
    colsum_kernel<<<(NN + 255) / 256, 256, 0, stream>>>(Hh, deg);
    scan1_kernel<<<NBLK, SCAN_B, 0, stream>>>(deg, rowptr, bsum);
    scan2_kernel<<<1, SCAN_B, 0, stream>>>(bsum, rowptr);
    scan3_kernel<<<NBLK, SCAN_B, 0, stream>>>(rowptr, bsum);
    offset_kernel<<<(NN + 255) / 256, 256, 0, stream>>>(Hh, rowptr);
    scatter2_kernel<<<P, 256, 0, stream>>>(ei, Hh, srcs);

    const int ggrid = (NN + 127) / 128;
    const int agrid = (NN + 3) / 4;

    // Layer 1
    gemm_fused_kernel<<<ggrid, 512, 0, stream>>>(x, W1, asrc1, adst1, hb, as_, ad_);
    aggregate_kernel<<<agrid, 256, 0, stream>>>(hb, as_, ad_, srcs, rowptr, b1, x2);

    // Layer 2
    gemm_fused_kernel<<<ggrid, 512, 0, stream>>>(x2, W2, asrc2, adst2, hb, as_, ad_);
    aggregate_kernel<<<agrid, 256, 0, stream>>>(hb, as_, ad_, srcs, rowptr, b2, x2);

    // Output projection
    out_gemm_kernel<<<(NN + 255) / 256, 256, 0, stream>>>(x2, Wout, bout, out);
}

// Round 18
// 332.347 us; speedup vs baseline: 1.1946x; 1.1946x over previous
//
#include <hip/hip_runtime.h>
#include <hip/hip_bf16.h>

// Problem constants (fixed by the reference)
#define NN 50000
#define EE 800000
#define E2 850000      // EE + NN self loops
#define HC 128         // HEADS*HIDDEN
#define HEADS 8
#define HID 16
#define NC 10
#define NEG_SLOPE 0.2f

#define SCAN_B 256
#define NBLK ((NN + SCAN_B - 1) / SCAN_B)   // 196

// Atomic-free CSR build. Round-17 lesson: P=64 monolithic blocks = 2.4%
// occupancy, latency-bound (77us). Now: 128 chunks x 2 bin-halves = 256
// blocks (1/CU), 512 thr = 8 waves each -> 2048 waves in flight.
#define NCH 128
#define CHUNK ((E2 + NCH - 1) / NCH)        // 6641
#define HALF 25000                          // 100 KB LDS histogram per block

// bf16 pack/unpack (H table stored as packed bf16x2 to halve gather bytes)
__device__ inline unsigned pack_bf16x2(float x, float y) {
    unsigned ux = __float_as_uint(x); ux = (ux + 0x7FFFu + ((ux >> 16) & 1u)) >> 16;
    unsigned uy = __float_as_uint(y); uy = (uy + 0x7FFFu + ((uy >> 16) & 1u)) >> 16;
    return ux | (uy << 16);
}
__device__ inline float bf_lo(unsigned u) { return __uint_as_float(u << 16); }
__device__ inline float bf_hi(unsigned u) { return __uint_as_float(u & 0xFFFF0000u); }

// ---------------------------------------------------------------------------
// CSR build v3. Block = (chunk, bin-half). Hh[chunk][node] counts->offsets.
// Hh ALIASES the hb/x2 float region (CSR completes before gemm writes hb).
// ---------------------------------------------------------------------------
__global__ __launch_bounds__(512) void hist_kernel(
    const int* __restrict__ ei, int* __restrict__ Hh)
{
    __shared__ int hist[HALF];
    const int chunk = blockIdx.x >> 1, base = (blockIdx.x & 1) * HALF;
    const int t = threadIdx.x;
    const int e0 = chunk * CHUNK;
    const int e1 = min(e0 + CHUNK, E2);
    for (int i = t; i < HALF; i += 512) hist[i] = 0;
    __syncthreads();
    for (int e = e0 + t; e < e1; e += 512) {
        int dst = (e < EE) ? ei[EE + e] : (e - EE);
        int d = dst - base;
        if (d >= 0 && d < HALF) atomicAdd(&hist[d], 1);   // LDS atomic
    }
    __syncthreads();
    int* outp = Hh + (size_t)chunk * NN + base;
    for (int i = t; i < HALF; i += 512) outp[i] = hist[i];
}

__global__ __launch_bounds__(256) void colsum_kernel(
    const int* __restrict__ Hh, int* __restrict__ deg)
{
    int n = blockIdx.x * 256 + threadIdx.x;
    if (n >= NN) return;
    int s = 0;
    #pragma unroll 8
    for (int b = 0; b < NCH; ++b) s += Hh[(size_t)b * NN + n];   // coalesced per b
    deg[n] = s;
}

__global__ __launch_bounds__(SCAN_B) void scan1_kernel(
    const int* __restrict__ deg, int* __restrict__ rowptr, int* __restrict__ bsum)
{
    __shared__ int sm[SCAN_B];
    const int b = blockIdx.x, t = threadIdx.x, i = b * SCAN_B + t;
    int v = (i < NN) ? deg[i] : 0;
    sm[t] = v;
    __syncthreads();
    for (int off = 1; off < SCAN_B; off <<= 1) {
        int x = (t >= off) ? sm[t - off] : 0;
        __syncthreads();
        sm[t] += x;
        __syncthreads();
    }
    if (i < NN) rowptr[i] = sm[t] - v;          // local exclusive
    if (t == SCAN_B - 1) bsum[b] = sm[t];       // block total
}

__global__ __launch_bounds__(SCAN_B) void scan2_kernel(
    int* __restrict__ bsum, int* __restrict__ rowptr)
{
    __shared__ int sm[SCAN_B];
    const int t = threadIdx.x;
    int v = (t < NBLK) ? bsum[t] : 0;
    sm[t] = v;
    __syncthreads();
    for (int off = 1; off < SCAN_B; off <<= 1) {
        int x = (t >= off) ? sm[t - off] : 0;
        __syncthreads();
        sm[t] += x;
        __syncthreads();
    }
    if (t < NBLK) bsum[t] = sm[t] - v;          // exclusive block offsets
    if (t == NBLK - 1) rowptr[NN] = sm[t];      // grand total (= E2)
}

__global__ __launch_bounds__(SCAN_B) void scan3_kernel(
    int* __restrict__ rowptr, const int* __restrict__ bsum)
{
    const int b = blockIdx.x, i = b * SCAN_B + threadIdx.x;
    if (i < NN) rowptr[i] += bsum[b];
}

// In-place: Hh[b][n] (count) -> global write offset for chunk b, node n
__global__ __launch_bounds__(256) void offset_kernel(
    int* __restrict__ Hh, const int* __restrict__ rowptr)
{
    int n = blockIdx.x * 256 + threadIdx.x;
    if (n >= NN) return;
    int run = rowptr[n];
    #pragma unroll 8
    for (int b = 0; b < NCH; ++b) {
        size_t idx = (size_t)b * NN + n;
        int c = Hh[idx];
        Hh[idx] = run;
        run += c;
    }
}

__global__ __launch_bounds__(512) void scatter_kernel(
    const int* __restrict__ ei, const int* __restrict__ Hh,
    int* __restrict__ srcs)
{
    __shared__ int hist[HALF];
    const int chunk = blockIdx.x >> 1, base = (blockIdx.x & 1) * HALF;
    const int t = threadIdx.x;
    const int e0 = chunk * CHUNK;
    const int e1 = min(e0 + CHUNK, E2);
    const int* offp = Hh + (size_t)chunk * NN;
    for (int i = t; i < HALF; i += 512) hist[i] = 0;
    __syncthreads();
    for (int e = e0 + t; e < e1; e += 512) {
        int src, dst;
        if (e < EE) { src = ei[e]; dst = ei[EE + e]; }
        else        { src = e - EE; dst = e - EE; }
        int d = dst - base;
        if (d >= 0 && d < HALF) {
            int rank = atomicAdd(&hist[d], 1);          // LDS atomic
            srcs[offp[dst] + rank] = src;               // plain store
        }
    }
}

// ---------------------------------------------------------------------------
// Fused GEMM (X[N,128] @ W[128,128]) + per-head alpha_src/alpha_dst dots.
// 512 threads, 131 KB LDS -> 1 block/CU, 2 waves/SIMD.
// H is written PACKED bf16 (row = 64 uints = 256 B) for the gather phase.
// ---------------------------------------------------------------------------
__global__ __launch_bounds__(512) void gemm_fused_kernel(
    const float* __restrict__ X, const float* __restrict__ W,
    const float* __restrict__ asrc, const float* __restrict__ adst,
    unsigned* __restrict__ Hb, float* __restrict__ AS, float* __restrict__ AD)
{
    __shared__ float Ws[8 * 2052];     // plane h: h*2052 + k*16 + j (bank-disjoint heads)
    __shared__ float Xst[128 * 128];   // Xst[k*128 + r]
    const int tid = threadIdx.x;
    const int row0 = blockIdx.x * 128;

    for (int i = tid; i < 4096; i += 512) {
        int k = i >> 5, q = i & 31;
        float4 v = ((const float4*)W)[i];
        *(float4*)&Ws[(q >> 2) * 2052 + k * 16 + (q & 3) * 4] = v;
    }
    {
        int r = tid & 127, quarter = tid >> 7;   // 0..3
        int row = row0 + r;
        if (row < NN) {
            const float4* xr = (const float4*)(X + (size_t)row * HC + quarter * 32);
            #pragma unroll
            for (int c4 = 0; c4 < 8; ++c4) {
                float4 v = xr[c4];
                int c = quarter * 32 + c4 * 4;
                Xst[(c + 0) * 128 + r] = v.x;
                Xst[(c + 1) * 128 + r] = v.y;
                Xst[(c + 2) * 128 + r] = v.z;
                Xst[(c + 3) * 128 + r] = v.w;
            }
        } else {
            #pragma unroll
            for (int c4 = 0; c4 < 8; ++c4) {
                int c = quarter * 32 + c4 * 4;
                Xst[(c + 0) * 128 + r] = 0.f;
                Xst[(c + 1) * 128 + r] = 0.f;
                Xst[(c + 2) * 128 + r] = 0.f;
                Xst[(c + 3) * 128 + r] = 0.f;
            }
        }
    }
    __syncthreads();

    const int rg = tid >> 3;     // 0..63 -> rows rg*2, rg*2+1
    const int head = tid & 7;
    float acc[2][16];
    #pragma unroll
    for (int i = 0; i < 2; ++i)
        #pragma unroll
        for (int j = 0; j < 16; ++j) acc[i][j] = 0.f;

    const float* wbase = &Ws[head * 2052];
    #pragma unroll 4
    for (int k = 0; k < 128; ++k) {
        float2 xv = *(const float2*)&Xst[k * 128 + rg * 2];
        const float* wp = wbase + k * 16;
        float4 w0 = *(const float4*)(wp + 0);
        float4 w1 = *(const float4*)(wp + 4);
        float4 w2 = *(const float4*)(wp + 8);
        float4 w3 = *(const float4*)(wp + 12);
        float xs[2] = {xv.x, xv.y};
        float ww[16] = {w0.x, w0.y, w0.z, w0.w, w1.x, w1.y, w1.z, w1.w,
                        w2.x, w2.y, w2.z, w2.w, w3.x, w3.y, w3.z, w3.w};
        #pragma unroll
        for (int i = 0; i < 2; ++i)
            #pragma unroll
            for (int j = 0; j < 16; ++j)
                acc[i][j] = fmaf(xs[i], ww[j], acc[i][j]);
    }

    // Epilogue: packed-bf16 H rows + fp32 per-head alpha dots
    #pragma unroll
    for (int i = 0; i < 2; ++i) {
        int row = row0 + rg * 2 + i;
        if (row >= NN) continue;
        unsigned* hp = Hb + (size_t)row * 64 + head * 8;
        uint4 p0 = make_uint4(pack_bf16x2(acc[i][0],  acc[i][1]),
                              pack_bf16x2(acc[i][2],  acc[i][3]),
                              pack_bf16x2(acc[i][4],  acc[i][5]),
                              pack_bf16x2(acc[i][6],  acc[i][7]));
        uint4 p1 = make_uint4(pack_bf16x2(acc[i][8],  acc[i][9]),
                              pack_bf16x2(acc[i][10], acc[i][11]),
                              pack_bf16x2(acc[i][12], acc[i][13]),
                              pack_bf16x2(acc[i][14], acc[i][15]));
        ((uint4*)hp)[0] = p0;
        ((uint4*)hp)[1] = p1;
        float s = 0.f, d = 0.f;
        #pragma unroll
        for (int j = 0; j < 16; ++j) {
            s = fmaf(acc[i][j], asrc[head * HID + j], s);
            d = fmaf(acc[i][j], adst[head * HID + j], d);
        }
        AS[row * HEADS + head] = s;
        AD[row * HEADS + head] = d;
    }
}

// ---------------------------------------------------------------------------
// Aggregation v3: 256-thread block = 4 independent waves, wave = one node.
// Lane covers 2 channels (one packed-bf16 uint = 4B coalesced load/edge).
// 4-way edge unroll -> 4 independent gather chains in flight per wave.
// ---------------------------------------------------------------------------
__global__ __launch_bounds__(256) void aggregate_kernel(
    const unsigned* __restrict__ Hb, const float* __restrict__ AS,
    const float* __restrict__ AD, const int* __restrict__ srcs,
    const int* __restrict__ rowptr, const float* __restrict__ bias,
    float* __restrict__ Out)
{
    const int wave = threadIdx.x >> 6;
    const int lane = threadIdx.x & 63;
    const int n = blockIdx.x * 4 + wave;
    if (n >= NN) return;
    const int head = lane >> 3;                 // head of channels 2*lane, 2*lane+1
    const int beg = rowptr[n], end = rowptr[n + 1];
    const float adv = AD[n * HEADS + head];

    float a0x = 0.f, a0y = 0.f, a1x = 0.f, a1y = 0.f;
    float a2x = 0.f, a2y = 0.f, a3x = 0.f, a3y = 0.f;
    float d0 = 0.f, d1 = 0.f, d2 = 0.f, d3 = 0.f;

    int s = beg;
    for (; s + 3 < end; s += 4) {
        int s0 = srcs[s], s1 = srcs[s + 1], s2 = srcs[s + 2], s3 = srcs[s + 3];
        float e0 = AS[s0 * HEADS + head] + adv;
        float e1 = AS[s1 * HEADS + head] + adv;
        float e2 = AS[s2 * HEADS + head] + adv;
        float e3 = AS[s3 * HEADS + head] + adv;
        unsigned h0 = Hb[(size_t)s0 * 64 + lane];
        unsigned h1 = Hb[(size_t)s1 * 64 + lane];
        unsigned h2 = Hb[(size_t)s2 * 64 + lane];
        unsigned h3 = Hb[(size_t)s3 * 64 + lane];
        e0 = (e0 >= 0.f) ? e0 : NEG_SLOPE * e0;
        e1 = (e1 >= 0.f) ? e1 : NEG_SLOPE * e1;
        e2 = (e2 >= 0.f) ? e2 : NEG_SLOPE * e2;
        e3 = (e3 >= 0.f) ? e3 : NEG_SLOPE * e3;
        float w0 = __expf(e0), w1 = __expf(e1), w2 = __expf(e2), w3 = __expf(e3);
        d0 += w0; d1 += w1; d2 += w2; d3 += w3;
        a0x = fmaf(w0, bf_lo(h0), a0x); a0y = fmaf(w0, bf_hi(h0), a0y);
        a1x = fmaf(w1, bf_lo(h1), a1x); a1y = fmaf(w1, bf_hi(h1), a1y);
        a2x = fmaf(w2, bf_lo(h2), a2x); a2y = fmaf(w2, bf_hi(h2), a2y);
        a3x = fmaf(w3, bf_lo(h3), a3x); a3y = fmaf(w3, bf_hi(h3), a3y);
    }
    for (; s < end; ++s) {
        int s0 = srcs[s];
        float e0 = AS[s0 * HEADS + head] + adv;
        unsigned h0 = Hb[(size_t)s0 * 64 + lane];
        e0 = (e0 >= 0.f) ? e0 : NEG_SLOPE * e0;
        float w0 = __expf(e0);
        d0 += w0;
        a0x = fmaf(w0, bf_lo(h0), a0x); a0y = fmaf(w0, bf_hi(h0), a0y);
    }
    float den = (d0 + d1) + (d2 + d3);
    float ax = (a0x + a1x) + (a2x + a3x);
    float ay = (a0y + a1y) + (a2y + a3y);
    float2 bv = *(const float2*)&bias[2 * lane];
    float ox = fmaxf(ax / den + bv.x, 0.f);
    float oy = fmaxf(ay / den + bv.y, 0.f);
    *(float2*)&Out[(size_t)n * HC + 2 * lane] = make_float2(ox, oy);
}

// ---------------------------------------------------------------------------
// Output GEMM: X[N,128] @ Wout[128,10] + bout
// ---------------------------------------------------------------------------
__global__ __launch_bounds__(256) void out_gemm_kernel(
    const float* __restrict__ X, const float* __restrict__ W,
    const float* __restrict__ b, float* __restrict__ Out)
{
    __shared__ float Ws[HC * NC];
    __shared__ float bs[NC];
    for (int i = threadIdx.x; i < HC * NC; i += 256) Ws[i] = W[i];
    if (threadIdx.x < NC) bs[threadIdx.x] = b[threadIdx.x];
    __syncthreads();
    int row = blockIdx.x * 256 + threadIdx.x;
    if (row >= NN) return;
    float acc[NC];
    #pragma unroll
    for (int j = 0; j < NC; ++j) acc[j] = bs[j];
    const float4* xr = (const float4*)(X + (size_t)row * HC);
    #pragma unroll 8
    for (int k4 = 0; k4 < 32; ++k4) {
        float4 v = xr[k4];
        const float* w0 = &Ws[(k4 * 4 + 0) * NC];
        const float* w1 = &Ws[(k4 * 4 + 1) * NC];
        const float* w2 = &Ws[(k4 * 4 + 2) * NC];
        const float* w3 = &Ws[(k4 * 4 + 3) * NC];
        #pragma unroll
        for (int j = 0; j < NC; ++j)
            acc[j] += v.x * w0[j] + v.y * w1[j] + v.z * w2[j] + v.w * w3[j];
    }
    float* op = Out + (size_t)row * NC;
    #pragma unroll
    for (int j = 0; j < NC; ++j) op[j] = acc[j];
}

// ---------------------------------------------------------------------------
extern "C" void kernel_launch(void* const* d_in, const int* in_sizes, int n_in,
                              void* d_out, int out_size, void* d_ws, size_t ws_size,
                              hipStream_t stream)
{
    const float* x      = (const float*)d_in[0];
    const int*   ei     = (const int*)d_in[1];   // edge_index as int32 [2,E]
    const float* W1     = (const float*)d_in[2];
    const float* asrc1  = (const float*)d_in[3];
    const float* adst1  = (const float*)d_in[4];
    const float* b1     = (const float*)d_in[5];
    const float* W2     = (const float*)d_in[6];
    const float* asrc2  = (const float*)d_in[7];
    const float* adst2  = (const float*)d_in[8];
    const float* b2     = (const float*)d_in[9];
    const float* Wout   = (const float*)d_in[10];
    const float* bout   = (const float*)d_in[11];
    float* out = (float*)d_out;

    // Float region: hb (N*64 u32) + x2 (N*128 f32) = 38.4 MB.
    // Hh (NCH*N ints = 25.6 MB) ALIASES it: CSR build finishes before
    // gemm_fused writes hb (stream-ordered), so no extra workspace.
    const size_t float_region = (size_t)NN * 64 * 4 + (size_t)NN * HC * 4;
    static_assert((size_t)NCH * NN * 4 <= (size_t)NN * 64 * 4 + (size_t)NN * HC * 4,
                  "Hh must fit in aliased float region");
    const size_t need_bytes =
        float_region +
        (size_t)NN * HEADS * 2 * sizeof(float) +
        ((size_t)(NN + 1) + NN + E2 + NBLK) * sizeof(int);
    if (ws_size < need_bytes) return;   // clean fail beats a memory fault

    unsigned* hb = (unsigned*)d_ws;                  // N*64 (packed bf16)
    int* Hh = (int*)d_ws;                            // NCH*N — aliases hb/x2
    float* x2  = (float*)(hb + (size_t)NN * 64);     // N*128
    float* as_ = x2 + (size_t)NN * HC;               // N*8
    float* ad_ = as_ + (size_t)NN * HEADS;           // N*8
    int* rowptr = (int*)(ad_ + (size_t)NN * HEADS);  // N+1
    int* deg    = rowptr + (NN + 1);                 // N
    int* srcs   = deg + NN;                          // E2
    int* bsum   = srcs + E2;                         // NBLK

    // CSR build — no global atomics, 256 blocks (chunk x half)
    hist_kernel<<<NCH * 2, 512, 0, stream>>>(ei, Hh);
    colsum_kernel<<<(NN + 255) / 256, 256, 0, stream>>>(Hh, deg);
    scan1_kernel<<<NBLK, SCAN_B, 0, stream>>>(deg, rowptr, bsum);
    scan2_kernel<<<1, SCAN_B, 0, stream>>>(bsum, rowptr);
    scan3_kernel<<<NBLK, SCAN_B, 0, stream>>>(rowptr, bsum);
    offset_kernel<<<(NN + 255) / 256, 256, 0, stream>>>(Hh, rowptr);
    scatter_kernel<<<NCH * 2, 512, 0, stream>>>(ei, Hh, srcs);

    const int ggrid = (NN + 127) / 128;
    const int agrid = (NN + 3) / 4;

    // Layer 1
    gemm_fused_kernel<<<ggrid, 512, 0, stream>>>(x, W1, asrc1, adst1, hb, as_, ad_);
    aggregate_kernel<<<agrid, 256, 0, stream>>>(hb, as_, ad_, srcs, rowptr, b1, x2);

    // Layer 2
    gemm_fused_kernel<<<ggrid, 512, 0, stream>>>(x2, W2, asrc2, adst2, hb, as_, ad_);
    aggregate_kernel<<<agrid, 256, 0, stream>>>(hb, as_, ad_, srcs, rowptr, b2, x2);

    // Output projection
    out_gemm_kernel<<<(NN + 255) / 256, 256, 0, stream>>>(x2, Wout, bout, out);
}